// Round 6
// baseline (424.509 us; speedup 1.0000x reference)
//
#include <hip/hip_runtime.h>
#include <math.h>

#define BB 4096
#define SEQ 50
#define KK 4
#define HH 64
#define NCOL (KK*SEQ)      // 200
#define NPART 16           // partial-sum groups over batch
#define BPP (BB/NPART)     // 256 batches per group
#define LDSTRIDE 260       // floats per staged row: 16B-aligned (1040 B), conflict-free

__device__ __forceinline__ float readlane_f32(float v, int lane) {
    return __int_as_float(__builtin_amdgcn_readlane(__float_as_int(v), lane));
}

// ---------------------------------------------------------------------------
// INIT: partial softmax denominators for iteration 0 (unshifted exp: |cw|
// stays < ~30 across iterations, exp fits fp32 comfortably) + zero the
// iter-1/2 partial accumulators. grid = NPART x 256; thread t < NCOL owns
// column t (coalesced across t).
// ---------------------------------------------------------------------------
__global__ void init_kernel(const float* __restrict__ cw,
                            float* __restrict__ part0,
                            float* __restrict__ part1,
                            float* __restrict__ part2) {
    const int p = blockIdx.x;
    const int t = threadIdx.x;
    if (t < NCOL) {
        const float* row = cw + (size_t)p * BPP * NCOL + t;
        float s = 0.f;
#pragma unroll 8
        for (int b = 0; b < BPP; b++) s += __expf(row[b * NCOL]);
        part0[p * NCOL + t] = s;
        part1[p * NCOL + t] = 0.f;
        part2[p * NCOL + t] = 0.f;
    }
}

// ---------------------------------------------------------------------------
// UPDATE (non-final): one routing iteration. grid = BB x 256; wave = k,
// lane = h. x[b] staged to LDS once (float4 + ds_write_b128); v-phase reads
// LDS b32 (banks (4s+h)%32 -> 2-way, free); delta reads x rows + v as b128
// (conflict-free per 128B phase). All cross-lane ops run with full exec
// (round-4 lesson); only final stores/atomics are guarded.
// ---------------------------------------------------------------------------
template <int ITER>   // 0,1 = routing update (writes cw + partials)
__global__ void update_kernel(const float* __restrict__ cw_src,
                              float* __restrict__ cw_dst,
                              const float* __restrict__ x,
                              const int* __restrict__ mask,
                              const float* __restrict__ part_in,
                              float* __restrict__ part_out) {
    const int b = blockIdx.x;
    const int k = threadIdx.x >> 6;
    const int h = threadIdx.x & 63;
    const int hs = (h < SEQ) ? h : 0;   // clamped seq index, keeps all lanes active

    __shared__ float lds_x[SEQ * LDSTRIDE];   // 52000 B
    __shared__ float vbuf[KK][HH];            // 1024 B

    // ---- stage x[b,:,:,:] (50 rows x 1KB) into LDS, float4 granularity ----
    const float* xg = x + (size_t)b * (SEQ * KK * HH);
#pragma unroll
    for (int i = 0; i < 13; i++) {
        const int idx = i * 256 + threadIdx.x;      // float4 chunk id
        if (idx < SEQ * 64) {
            const int r = idx >> 6, c = idx & 63;
            const float4 g = *(const float4*)(xg + r * (KK * HH) + c * 4);
            *(float4*)&lds_x[r * LDSTRIDE + c * 4] = g;
        }
    }

    // ---- own-column softmax denominator: col = k*SEQ+hs, 16 partials ----
    const int col = k * SEQ + hs;
    float den = 0.f;
#pragma unroll
    for (int p = 0; p < NPART; p++) den += part_in[p * NCOL + col];

    const float c0 = cw_src[(size_t)b * NCOL + col];
    const int  mk = mask[b * SEQ + hs];

    __syncthreads();   // staging visible to all waves

    const float e = __expf(c0) / den;
    const float wlane = (h < SEQ && mk != 0) ? e : 0.f;

    // ---- v_h = sum_s w_s * x[s,k,h]  (LDS b32, w via readlane) ----
    float v = 0.f;
#pragma unroll
    for (int s = 0; s < SEQ; s++)
        v = fmaf(readlane_f32(wlane, s), lds_x[s * LDSTRIDE + k * HH + h], v);

    // ---- squash ----
    float n2 = v * v;
#pragma unroll
    for (int off = 32; off >= 1; off >>= 1) n2 += __shfl_xor(n2, off, 64);
    const float scalar = n2 / ((1.f + n2) * sqrtf(n2 + 1e-9f));
    v *= scalar;

    // ---- delta_s = x[s,k,:] . v at lane s, via LDS b128 ----
    vbuf[k][h] = v;                 // per-wave region; same-wave RAW, no barrier
    const float* xrow = &lds_x[hs * LDSTRIDE + k * HH];
    float g16[16];
#pragma unroll
    for (int j4 = 0; j4 < 16; j4++) {
        const float4 xv = *(const float4*)(xrow + 4 * j4);
        const float4 vv = *(const float4*)&vbuf[k][4 * j4];
        g16[j4] = (xv.x * vv.x + xv.y * vv.y) + (xv.z * vv.z + xv.w * vv.w);
    }
    float t8[8], t4[4];
#pragma unroll
    for (int i = 0; i < 8; i++) t8[i] = g16[2 * i] + g16[2 * i + 1];
#pragma unroll
    for (int i = 0; i < 4; i++) t4[i] = t8[2 * i] + t8[2 * i + 1];
    const float del = (t4[0] + t4[1]) + (t4[2] + t4[3]);

    if (h < SEQ) {
        const float nc = c0 + del;
        cw_dst[(size_t)b * NCOL + col] = nc;
        atomicAdd(&part_out[(b >> 8) * NCOL + col], __expf(nc));  // BB/NPART=256 per group
    }
}

// ---------------------------------------------------------------------------
// FINAL: compute out = squash(w . x). Direct global loads (no delta, no LDS x).
// ---------------------------------------------------------------------------
__global__ void final_kernel(const float* __restrict__ cw_src,
                             const float* __restrict__ x,
                             const int* __restrict__ mask,
                             const float* __restrict__ part_in,
                             float* __restrict__ out) {
    const int b = blockIdx.x;
    const int k = threadIdx.x >> 6;
    const int h = threadIdx.x & 63;
    const int hs = (h < SEQ) ? h : 0;

    const int col = k * SEQ + hs;
    float den = 0.f;
#pragma unroll
    for (int p = 0; p < NPART; p++) den += part_in[p * NCOL + col];

    const float c0 = cw_src[(size_t)b * NCOL + col];
    const int  mk = mask[b * SEQ + hs];
    const float e = __expf(c0) / den;
    const float wlane = (h < SEQ && mk != 0) ? e : 0.f;

    const float* xp = x + (size_t)b * (SEQ * KK * HH) + k * HH + h;
    float v = 0.f;
#pragma unroll
    for (int s = 0; s < SEQ; s++)
        v = fmaf(readlane_f32(wlane, s), xp[s * (KK * HH)], v);

    float n2 = v * v;
#pragma unroll
    for (int off = 32; off >= 1; off >>= 1) n2 += __shfl_xor(n2, off, 64);
    const float scalar = n2 / ((1.f + n2) * sqrtf(n2 + 1e-9f));
    out[(size_t)b * (KK * HH) + k * HH + h] = v * scalar;
}

extern "C" void kernel_launch(void* const* d_in, const int* in_sizes, int n_in,
                              void* d_out, int out_size, void* d_ws, size_t ws_size,
                              hipStream_t stream) {
    const int*   mask  = (const int*)d_in[0];
    const float* x     = (const float*)d_in[1];
    const float* cw_in = (const float*)d_in[2];
    float* out = (float*)d_out;

    float* cw_ws = (float*)d_ws;                       // BB*NCOL floats
    float* part0 = cw_ws + (size_t)BB * NCOL;          // NPART*NCOL each
    float* part1 = part0 + NPART * NCOL;
    float* part2 = part1 + NPART * NCOL;

    init_kernel<<<NPART, 256, 0, stream>>>(cw_in, part0, part1, part2);
    update_kernel<0><<<BB, 256, 0, stream>>>(cw_in, cw_ws, x, mask, part0, part1);
    update_kernel<1><<<BB, 256, 0, stream>>>(cw_ws, cw_ws, x, mask, part1, part2);
    final_kernel<<<BB, 256, 0, stream>>>(cw_ws, x, mask, part2, out);
}